// Round 7
// baseline (294.177 us; speedup 1.0000x reference)
//
#include <hip/hip_runtime.h>
#include <hip/hip_fp16.h>

#define NN 262144
#define NE 4194304
#define NLOGIT 4
#define NHID 16
#define ND 20   // NLOGIT + NHID
#define ND2 40  // 2*ND

#define NBUCK 512          // buckets
#define BSHIFT 9           // bucket = receiver >> BSHIFT
#define RPB 512            // receivers per bucket (NN / NBUCK)
#define SBITS 18           // sender id bits (NN = 2^18)
#define SMASK ((1u << SBITS) - 1)
#define FBLK 1024          // fill blocks (== gather block's thread count)
#define EPB (NE / FBLK)    // 4096 edges per fill block
#define EPT (EPB / 256)    // 16 edges per thread
#define CAP 9728           // per-bucket LDS edge capacity (mean 8192, +17 sigma)

#define NSL 4              // sender slices (64K senders = 4.2 MB msgh per slice)
#define SLSH 16            // slice = sender >> SLSH
#define NKEY (NSL * RPB)   // 2048 (slice, receiver) keys

#define NPB 128            // nodes per MLP block
#define XS 132             // padded LDS column stride

#define MROW 16            // msg row = 16 uint32 = 32 halfs = 64 B (one cache line)

__device__ __forceinline__ void lds_fill(float* dst, const float* src, int n, int tid, int nthreads) {
    for (int i = tid; i < n; i += nthreads) dst[i] = src[i];
}

// ---------------------------------------------------------------------------
// Register-blocked 3-layer MLP core over a 128-node LDS tile.
// ---------------------------------------------------------------------------
template<int IN>
__device__ __forceinline__ void mlp3_core(
    const int tid, const float* Xl, float* H1, float* H2, float* Ol,
    const float* sW1, const float* sb1,
    const float* sW2, const float* sb2,
    const float* sW3, const float* sb3)
{
    const int q = tid & 31;
    const int g = tid >> 5;
    const int n0 = q * 4;

    // ---- layer 1: IN -> 64, feats g*8 .. g*8+7, nodes n0..n0+3
    float a1[8][4];
    #pragma unroll
    for (int f = 0; f < 8; f++) {
        const float b = sb1[g * 8 + f];
        a1[f][0] = b; a1[f][1] = b; a1[f][2] = b; a1[f][3] = b;
    }
    #pragma unroll
    for (int i = 0; i < IN; i++) {
        const float4 xv = *reinterpret_cast<const float4*>(&Xl[i * XS + n0]);
        const float4 w0 = *reinterpret_cast<const float4*>(&sW1[i * 64 + g * 8]);
        const float4 w1 = *reinterpret_cast<const float4*>(&sW1[i * 64 + g * 8 + 4]);
        const float wf[8] = {w0.x, w0.y, w0.z, w0.w, w1.x, w1.y, w1.z, w1.w};
        #pragma unroll
        for (int f = 0; f < 8; f++) {
            a1[f][0] = fmaf(xv.x, wf[f], a1[f][0]);
            a1[f][1] = fmaf(xv.y, wf[f], a1[f][1]);
            a1[f][2] = fmaf(xv.z, wf[f], a1[f][2]);
            a1[f][3] = fmaf(xv.w, wf[f], a1[f][3]);
        }
    }
    #pragma unroll
    for (int f = 0; f < 8; f++) {
        float4 v = make_float4(fmaxf(a1[f][0], 0.f), fmaxf(a1[f][1], 0.f),
                               fmaxf(a1[f][2], 0.f), fmaxf(a1[f][3], 0.f));
        *reinterpret_cast<float4*>(&H1[(g * 8 + f) * XS + n0]) = v;
    }
    __syncthreads();   // H1 complete; Xl dead from here (H2 may alias it)

    // ---- layer 2: 64 -> 32, feats g*4 .. g*4+3
    float a2[4][4];
    #pragma unroll
    for (int f = 0; f < 4; f++) {
        const float b = sb2[g * 4 + f];
        a2[f][0] = b; a2[f][1] = b; a2[f][2] = b; a2[f][3] = b;
    }
    #pragma unroll
    for (int i = 0; i < 64; i++) {
        const float4 xv = *reinterpret_cast<const float4*>(&H1[i * XS + n0]);
        const float4 w = *reinterpret_cast<const float4*>(&sW2[i * 32 + g * 4]);
        const float wf[4] = {w.x, w.y, w.z, w.w};
        #pragma unroll
        for (int f = 0; f < 4; f++) {
            a2[f][0] = fmaf(xv.x, wf[f], a2[f][0]);
            a2[f][1] = fmaf(xv.y, wf[f], a2[f][1]);
            a2[f][2] = fmaf(xv.z, wf[f], a2[f][2]);
            a2[f][3] = fmaf(xv.w, wf[f], a2[f][3]);
        }
    }
    #pragma unroll
    for (int f = 0; f < 4; f++) {
        float4 v = make_float4(fmaxf(a2[f][0], 0.f), fmaxf(a2[f][1], 0.f),
                               fmaxf(a2[f][2], 0.f), fmaxf(a2[f][3], 0.f));
        *reinterpret_cast<float4*>(&H2[(g * 4 + f) * XS + n0]) = v;
    }
    __syncthreads();   // H2 complete

    // ---- layer 3: 32 -> 20, groups 0..4 active, feats g*4 .. g*4+3
    float a3[4][4];
    if (g < 5) {
        #pragma unroll
        for (int f = 0; f < 4; f++) {
            const float b = sb3[g * 4 + f];
            a3[f][0] = b; a3[f][1] = b; a3[f][2] = b; a3[f][3] = b;
        }
        #pragma unroll
        for (int i = 0; i < 32; i++) {
            const float4 xv = *reinterpret_cast<const float4*>(&H2[i * XS + n0]);
            const float4 w = *reinterpret_cast<const float4*>(&sW3[i * 20 + g * 4]);
            const float wf[4] = {w.x, w.y, w.z, w.w};
            #pragma unroll
            for (int f = 0; f < 4; f++) {
                a3[f][0] = fmaf(xv.x, wf[f], a3[f][0]);
                a3[f][1] = fmaf(xv.y, wf[f], a3[f][1]);
                a3[f][2] = fmaf(xv.z, wf[f], a3[f][2]);
                a3[f][3] = fmaf(xv.w, wf[f], a3[f][3]);
            }
        }
    }
    __syncthreads();   // all H2 reads done; Ol may alias H2
    if (g < 5) {
        #pragma unroll
        for (int f = 0; f < 4; f++) {
            #pragma unroll
            for (int k = 0; k < 4; k++)
                Ol[(n0 + k) * ND + g * 4 + f] = a3[f][k];
        }
    }
    __syncthreads();   // Ol ready for epilogue
}

// ---------------------------------------------------------------------------
// Kernel 1: edge-message MLP (20 -> 64 -> 32 -> 20), 128 nodes per block.
// Output: fp16-packed msg rows, 32 half slots (64 B, one line) per node.
// ---------------------------------------------------------------------------
__global__ __launch_bounds__(256) void msg_mlp_kernel(
    const float* __restrict__ logits, const float* __restrict__ hidden,
    const float* __restrict__ W1, const float* __restrict__ b1,
    const float* __restrict__ W2, const float* __restrict__ b2,
    const float* __restrict__ W3, const float* __restrict__ b3,
    unsigned int* __restrict__ msgh)
{
    __shared__ float regA[32 * XS];
    __shared__ float H1[64 * XS];
    __shared__ float sW1[ND * 64], sb1[64], sW2[64 * 32], sb2[32], sW3[32 * ND], sb3[ND];
    const int tid = threadIdx.x;
    const int nb0 = blockIdx.x * NPB;

    lds_fill(sW1, W1, ND * 64, tid, 256);
    lds_fill(sb1, b1, 64, tid, 256);
    lds_fill(sW2, W2, 64 * 32, tid, 256);
    lds_fill(sb2, b2, 32, tid, 256);
    lds_fill(sW3, W3, 32 * ND, tid, 256);
    lds_fill(sb3, b3, ND, tid, 256);

    float* Xl = regA;
    if (tid < NPB) {
        const float4 lv = reinterpret_cast<const float4*>(logits)[nb0 + tid];
        Xl[0 * XS + tid] = lv.x; Xl[1 * XS + tid] = lv.y;
        Xl[2 * XS + tid] = lv.z; Xl[3 * XS + tid] = lv.w;
    }
    #pragma unroll
    for (int u = 0; u < 2; u++) {
        const int idx = u * 256 + tid;
        const int n = idx >> 2, qq = idx & 3;
        const float4 hv = reinterpret_cast<const float4*>(hidden)[(size_t)(nb0 + n) * 4 + qq];
        Xl[(4 + qq * 4 + 0) * XS + n] = hv.x;
        Xl[(4 + qq * 4 + 1) * XS + n] = hv.y;
        Xl[(4 + qq * 4 + 2) * XS + n] = hv.z;
        Xl[(4 + qq * 4 + 3) * XS + n] = hv.w;
    }
    __syncthreads();

    mlp3_core<ND>(tid, Xl, H1, regA /*H2*/, regA /*Ol*/, sW1, sb1, sW2, sb2, sW3, sb3);

    // epilogue: pack fp16 rows. NPB nodes x 16 uint32 = 2048 words.
    unsigned int* mo = msgh + (size_t)nb0 * MROW;
    #pragma unroll
    for (int idx = tid; idx < NPB * MROW; idx += 256) {
        const int n = idx >> 4, slot = idx & 15;
        const int c = slot * 2;
        float v0 = 0.f, v1 = 0.f;
        if (c < ND) { v0 = regA[n * ND + c]; v1 = regA[n * ND + c + 1]; }
        __half2 h = __floats2half2_rn(v0, v1);
        mo[idx] = *reinterpret_cast<unsigned int*>(&h);
    }
}

// ---------------------------------------------------------------------------
// Kernel 2: bucket fill (block-major). Each block counting-sorts its 4096
// edges by bucket in LDS and writes ONE contiguous coalesced 16 KB run.
// ---------------------------------------------------------------------------
__global__ __launch_bounds__(256) void bucket_fill_kernel(
    const int* __restrict__ senders, const int* __restrict__ receivers,
    unsigned int* __restrict__ bucketed, unsigned int* __restrict__ tab)
{
    __shared__ int cnt[NBUCK];
    __shared__ int boff[NBUCK];
    __shared__ int lcur[NBUCK];
    __shared__ int psum[256];
    __shared__ unsigned int sorted[EPB];   // 16 KB
    const int tid = threadIdx.x;
    const int blk = blockIdx.x;

    cnt[tid] = 0; cnt[256 + tid] = 0;
    __syncthreads();

    int rr[EPT], ss[EPT];
    const int base = blk * EPB;
    #pragma unroll
    for (int k = 0; k < EPT; k++) {
        rr[k] = receivers[base + k * 256 + tid];
        ss[k] = senders[base + k * 256 + tid];
        atomicAdd(&cnt[rr[k] >> BSHIFT], 1);
    }
    __syncthreads();

    const int c0 = cnt[2 * tid], c1 = cnt[2 * tid + 1];
    psum[tid] = c0 + c1;
    __syncthreads();
    #pragma unroll
    for (int off = 1; off < 256; off <<= 1) {
        int t = (tid >= off) ? psum[tid - off] : 0;
        __syncthreads();
        psum[tid] += t;
        __syncthreads();
    }
    const int ex = psum[tid] - (c0 + c1);
    boff[2 * tid] = ex;       boff[2 * tid + 1] = ex + c0;
    lcur[2 * tid] = ex;       lcur[2 * tid + 1] = ex + c0;
    __syncthreads();

    tab[(size_t)blk * NBUCK + tid] =
        ((unsigned int)boff[tid] << 16) | (unsigned int)cnt[tid];
    tab[(size_t)blk * NBUCK + 256 + tid] =
        ((unsigned int)boff[256 + tid] << 16) | (unsigned int)cnt[256 + tid];

    #pragma unroll
    for (int k = 0; k < EPT; k++) {
        const int b = rr[k] >> BSHIFT;
        const int slot = atomicAdd(&lcur[b], 1);
        sorted[slot] = (((unsigned int)(rr[k] & (RPB - 1))) << SBITS) | (unsigned int)ss[k];
    }
    __syncthreads();

    const uint4* s4 = reinterpret_cast<const uint4*>(sorted);
    uint4* o4 = reinterpret_cast<uint4*>(bucketed + (size_t)blk * EPB);
    #pragma unroll
    for (int k = 0; k < EPB / 4 / 256; k++)
        o4[k * 256 + tid] = s4[k * 256 + tid];
}

// ---------------------------------------------------------------------------
// Kernel 3: transpose tab [FBLK][NBUCK] -> tabT [NBUCK][FBLK] (LDS-tiled).
// ---------------------------------------------------------------------------
__global__ __launch_bounds__(256) void transpose_tab_kernel(
    const unsigned int* __restrict__ in, unsigned int* __restrict__ out)
{
    __shared__ unsigned int t[32][33];
    const int tx = threadIdx.x & 31;
    const int ty0 = (threadIdx.x >> 5) * 4;
    const int bb = blockIdx.x * 32;   // bucket base
    const int kb = blockIdx.y * 32;   // blk base
    #pragma unroll
    for (int k = 0; k < 4; k++)
        t[ty0 + k][tx] = in[(size_t)(kb + ty0 + k) * NBUCK + bb + tx];
    __syncthreads();
    #pragma unroll
    for (int k = 0; k < 4; k++)
        out[(size_t)(bb + ty0 + k) * FBLK + kb + tx] = t[tx][ty0 + k];
}

// ---------------------------------------------------------------------------
// Kernel 4: slice-phased per-bucket group + gather. One block (1024 thr)
// per bucket. Edges grouped by (sender-slice, receiver) in LDS; the gather
// sweeps slice-major so concurrently-running blocks confine their msgh
// reads to one 4.2 MB slice at a time (per-XCD L2 resident).
// ---------------------------------------------------------------------------
__global__ __launch_bounds__(1024) void bucket_gather_kernel(
    const unsigned int* __restrict__ bucketed,
    const unsigned int* __restrict__ tabT,
    const unsigned int* __restrict__ msgh, float* __restrict__ agg)
{
    __shared__ unsigned int elds[CAP];
    __shared__ int dcnt[NKEY];
    __shared__ int dcur[NKEY];
    __shared__ int psum[1024];
    const int tid = threadIdx.x;
    const int b = blockIdx.x;

    const unsigned int tv = tabT[(size_t)b * FBLK + tid];
    const int segc = tv & 0xFFFF;
    const unsigned int* seg = bucketed + (size_t)tid * EPB + (tv >> 16);

    dcnt[tid] = 0; dcnt[1024 + tid] = 0;
    __syncthreads();
    for (int i = 0; i < segc; i++) {
        const unsigned int v = seg[i];
        const int key = (int)((v & SMASK) >> SLSH) * RPB + (int)(v >> SBITS);
        atomicAdd(&dcnt[key], 1);
    }
    __syncthreads();
    // exclusive scan over 2048 keys (2 per thread + Hillis-Steele 1024)
    const int c0 = dcnt[2 * tid], c1 = dcnt[2 * tid + 1];
    psum[tid] = c0 + c1;
    __syncthreads();
    #pragma unroll
    for (int off = 1; off < 1024; off <<= 1) {
        int t = (tid >= off) ? psum[tid - off] : 0;
        __syncthreads();
        psum[tid] += t;
        __syncthreads();
    }
    const int ex = psum[tid] - (c0 + c1);
    dcur[2 * tid] = ex; dcur[2 * tid + 1] = ex + c0;
    __syncthreads();
    for (int i = 0; i < segc; i++) {
        const unsigned int v = seg[i];
        const int key = (int)((v & SMASK) >> SLSH) * RPB + (int)(v >> SBITS);
        const int slot = atomicAdd(&dcur[key], 1);
        if (slot < CAP) elds[slot] = v & SMASK;
    }
    __syncthreads();

    // gather: half-wave groups; lanes 0..9 handle comps 2c,2c+1.
    // Receiver space in 2 halves of 256; within a half, sweep slices 0..3.
    const int hw = tid >> 5;          // 0..31
    const int c = tid & 31;
    const bool act = c < ND / 2;
    #pragma unroll
    for (int h = 0; h < 2; h++) {
        float2 acc[8];
        #pragma unroll
        for (int j = 0; j < 8; j++) acc[j] = make_float2(0.f, 0.f);
        for (int s = 0; s < NSL; s++) {
            #pragma unroll
            for (int j = 0; j < 8; j++) {
                const int rl = h * 256 + j * 32 + hw;
                const int key = s * RPB + rl;
                int end = dcur[key];
                const int cv = dcnt[key];
                int st = end - cv;
                if (st < 0) st = 0;
                if (end > CAP) end = CAP;
                float a00 = 0.f, a01 = 0.f, a10 = 0.f, a11 = 0.f;
                int i = st;
                for (; i + 1 < end; i += 2) {
                    const int s0 = elds[i];
                    const int s1 = elds[i + 1];
                    if (act) {
                        const unsigned int w0 = msgh[s0 * MROW + c];
                        const unsigned int w1 = msgh[s1 * MROW + c];
                        const float2 f0 = __half22float2(*reinterpret_cast<const __half2*>(&w0));
                        const float2 f1 = __half22float2(*reinterpret_cast<const __half2*>(&w1));
                        a00 += f0.x; a01 += f0.y;
                        a10 += f1.x; a11 += f1.y;
                    }
                }
                if (i < end) {
                    const int s0 = elds[i];
                    if (act) {
                        const unsigned int w = msgh[s0 * MROW + c];
                        const float2 f = __half22float2(*reinterpret_cast<const __half2*>(&w));
                        a00 += f.x; a01 += f.y;
                    }
                }
                if (act) { acc[j].x += a00 + a10; acc[j].y += a01 + a11; }
            }
            __syncthreads();   // slice phase boundary (keeps waves aligned)
        }
        if (act) {
            #pragma unroll
            for (int j = 0; j < 8; j++) {
                const int rl = h * 256 + j * 32 + hw;
                *reinterpret_cast<float2*>(&agg[((size_t)b * RPB + rl) * ND + 2 * c]) = acc[j];
            }
        }
    }
}

// ---------------------------------------------------------------------------
// Kernel 5: node output MLP (40 -> 64 -> 32 -> 20), 128 nodes per block.
// ---------------------------------------------------------------------------
__global__ __launch_bounds__(256) void node_mlp_kernel(
    const float* __restrict__ logits, const float* __restrict__ hidden,
    const float* __restrict__ agg,
    const float* __restrict__ W1, const float* __restrict__ b1,
    const float* __restrict__ W2, const float* __restrict__ b2,
    const float* __restrict__ W3, const float* __restrict__ b3,
    float* __restrict__ out)
{
    __shared__ float regA[ND2 * XS];
    __shared__ float H1[64 * XS];
    __shared__ float sW1[ND2 * 64], sb1[64], sW2[64 * 32], sb2[32], sW3[32 * ND], sb3[ND];
    const int tid = threadIdx.x;
    const int nb0 = blockIdx.x * NPB;

    lds_fill(sW1, W1, ND2 * 64, tid, 256);
    lds_fill(sb1, b1, 64, tid, 256);
    lds_fill(sW2, W2, 64 * 32, tid, 256);
    lds_fill(sb2, b2, 32, tid, 256);
    lds_fill(sW3, W3, 32 * ND, tid, 256);
    lds_fill(sb3, b3, ND, tid, 256);

    float* Xl = regA;
    if (tid < NPB) {
        const float4 lv = reinterpret_cast<const float4*>(logits)[nb0 + tid];
        Xl[0 * XS + tid] = lv.x; Xl[1 * XS + tid] = lv.y;
        Xl[2 * XS + tid] = lv.z; Xl[3 * XS + tid] = lv.w;
    }
    #pragma unroll
    for (int u = 0; u < 2; u++) {
        const int idx = u * 256 + tid;
        const int n = idx >> 2, qq = idx & 3;
        const float4 hv = reinterpret_cast<const float4*>(hidden)[(size_t)(nb0 + n) * 4 + qq];
        Xl[(4 + qq * 4 + 0) * XS + n] = hv.x;
        Xl[(4 + qq * 4 + 1) * XS + n] = hv.y;
        Xl[(4 + qq * 4 + 2) * XS + n] = hv.z;
        Xl[(4 + qq * 4 + 3) * XS + n] = hv.w;
    }
    for (int idx = tid; idx < NPB * 5; idx += 256) {
        const int n = idx / 5, qq = idx % 5;
        const float4 av = reinterpret_cast<const float4*>(agg)[(size_t)(nb0 + n) * 5 + qq];
        Xl[(ND + qq * 4 + 0) * XS + n] = av.x;
        Xl[(ND + qq * 4 + 1) * XS + n] = av.y;
        Xl[(ND + qq * 4 + 2) * XS + n] = av.z;
        Xl[(ND + qq * 4 + 3) * XS + n] = av.w;
    }
    __syncthreads();

    mlp3_core<ND2>(tid, Xl, H1, regA /*H2*/, regA /*Ol*/, sW1, sb1, sW2, sb2, sW3, sb3);

    if (tid < NPB) {
        const float* orow = regA + tid * ND;
        reinterpret_cast<float4*>(out)[nb0 + tid] =
            make_float4(orow[0], orow[1], orow[2], orow[3]);
        float4* ho = reinterpret_cast<float4*>(out + (size_t)NN * NLOGIT + (size_t)(nb0 + tid) * NHID);
        #pragma unroll
        for (int k = 0; k < 4; k++)
            ho[k] = make_float4(orow[4 + k*4 + 0], orow[4 + k*4 + 1],
                                orow[4 + k*4 + 2], orow[4 + k*4 + 3]);
    }
}

extern "C" void kernel_launch(void* const* d_in, const int* in_sizes, int n_in,
                              void* d_out, int out_size, void* d_ws, size_t ws_size,
                              hipStream_t stream) {
    const float* logits   = (const float*)d_in[0];
    const float* hidden   = (const float*)d_in[1];
    const int*   senders  = (const int*)d_in[2];
    const int*   receivers= (const int*)d_in[3];
    const float* We1 = (const float*)d_in[4];
    const float* be1 = (const float*)d_in[5];
    const float* We2 = (const float*)d_in[6];
    const float* be2 = (const float*)d_in[7];
    const float* We3 = (const float*)d_in[8];
    const float* be3 = (const float*)d_in[9];
    const float* Wn1 = (const float*)d_in[10];
    const float* bn1 = (const float*)d_in[11];
    const float* Wn2 = (const float*)d_in[12];
    const float* bn2 = (const float*)d_in[13];
    const float* Wn3 = (const float*)d_in[14];
    const float* bn3 = (const float*)d_in[15];
    float* out = (float*)d_out;

    // Workspace layout (~58.6 MB)
    unsigned int* msgh = (unsigned int*)d_ws;          // NN*MROW u32 (16.8 MB, 64B rows)
    float* agg = (float*)(msgh + (size_t)NN * MROW);   // NN*ND floats (21 MB)
    unsigned int* bucketed = (unsigned int*)(agg + (size_t)NN * ND);  // NE u32 (16.8 MB)
    unsigned int* tab  = bucketed + NE;                // FBLK*NBUCK u32 (2 MB)
    unsigned int* tabT = tab + (size_t)FBLK * NBUCK;   // NBUCK*FBLK u32 (2 MB)

    msg_mlp_kernel<<<NN / NPB, 256, 0, stream>>>(
        logits, hidden, We1, be1, We2, be2, We3, be3, msgh);
    bucket_fill_kernel<<<FBLK, 256, 0, stream>>>(senders, receivers, bucketed, tab);
    transpose_tab_kernel<<<dim3(NBUCK / 32, FBLK / 32), 256, 0, stream>>>(tab, tabT);
    bucket_gather_kernel<<<NBUCK, 1024, 0, stream>>>(bucketed, tabT, msgh, agg);
    node_mlp_kernel<<<NN / NPB, 256, 0, stream>>>(
        logits, hidden, agg, Wn1, bn1, Wn2, bn2, Wn3, bn3, out);
}

// Round 8
// 220.049 us; speedup vs baseline: 1.3369x; 1.3369x over previous
//
#include <hip/hip_runtime.h>
#include <hip/hip_fp16.h>

#define NN 262144
#define NE 4194304
#define NLOGIT 4
#define NHID 16
#define ND 20   // NLOGIT + NHID
#define ND2 40  // 2*ND

#define NBUCK 512          // buckets
#define BSHIFT 9           // bucket = receiver >> BSHIFT
#define RPB 512            // receivers per bucket (NN / NBUCK)
#define SBITS 18           // sender id bits (NN = 2^18)
#define SMASK ((1u << SBITS) - 1)
#define FBLK 1024          // fill blocks (== gather block's thread count)
#define EPB (NE / FBLK)    // 4096 edges per fill block
#define EPT (EPB / 256)    // 16 edges per thread
#define CAP 9728           // per-bucket LDS edge capacity (mean 8192, +17 sigma)

#define MROW 16            // msg row = 16 uint32 = 32 halfs = 64 B (one cache line)

// ---------------------------------------------------------------------------
// 4-input-row FMA block: h1[64] += xc.{x,y,z,w} * W[0..3][64].
// Wb is wave-uniform -> scalar (s_load) path; h1 static-indexed (registers).
// ---------------------------------------------------------------------------
__device__ __forceinline__ void fma4_64(float* h1, const float4 xc, const float* __restrict__ Wb) {
    #pragma unroll
    for (int j = 0; j < 64; j++) {
        float acc = h1[j];
        acc = fmaf(xc.x, Wb[j], acc);
        acc = fmaf(xc.y, Wb[64 + j], acc);
        acc = fmaf(xc.z, Wb[128 + j], acc);
        acc = fmaf(xc.w, Wb[192 + j], acc);
        h1[j] = acc;
    }
}

// L2 (64 -> 32, ReLU) and L3 (32 -> 20) shared tail. All static indexing.
__device__ __forceinline__ void mlp_tail(
    const float* h1, float* o,
    const float* __restrict__ W2, const float* __restrict__ b2,
    const float* __restrict__ W3, const float* __restrict__ b3)
{
    float h2[32];
    #pragma unroll
    for (int j = 0; j < 32; j++) h2[j] = b2[j];
    #pragma unroll
    for (int i = 0; i < 64; i++) {
        const float hi = h1[i];
        #pragma unroll
        for (int j = 0; j < 32; j++) h2[j] = fmaf(hi, W2[i * 32 + j], h2[j]);
    }
    #pragma unroll
    for (int j = 0; j < 32; j++) h2[j] = fmaxf(h2[j], 0.f);

    #pragma unroll
    for (int j = 0; j < ND; j++) o[j] = b3[j];
    #pragma unroll
    for (int i = 0; i < 32; i++) {
        const float hi = h2[i];
        #pragma unroll
        for (int j = 0; j < ND; j++) o[j] = fmaf(hi, W3[i * ND + j], o[j]);
    }
}

// ---------------------------------------------------------------------------
// Kernel 1: edge-message MLP (20 -> 64 -> 32 -> 20), 1 thread = 1 node.
// Weights via uniform (scalar-pipe) loads; no LDS except output staging.
// Output: fp16-packed msg rows, 32 half slots (64 B, one line) per node.
// ---------------------------------------------------------------------------
__global__ __launch_bounds__(256) void msg_mlp_kernel(
    const float* __restrict__ logits, const float* __restrict__ hidden,
    const float* __restrict__ W1, const float* __restrict__ b1,
    const float* __restrict__ W2, const float* __restrict__ b2,
    const float* __restrict__ W3, const float* __restrict__ b3,
    unsigned int* __restrict__ msgh)
{
    __shared__ float Ol[256 * ND];   // 20 KB output staging
    const int tid = threadIdx.x;
    const int n = blockIdx.x * 256 + tid;

    float h1[64];
    #pragma unroll
    for (int j = 0; j < 64; j++) h1[j] = b1[j];

    {   // logits rows 0..3
        const float4 xc = reinterpret_cast<const float4*>(logits)[n];
        fma4_64(h1, xc, W1);
    }
    #pragma unroll 1
    for (int c = 0; c < 4; c++) {   // hidden rows 4..19
        const float4 xc = reinterpret_cast<const float4*>(hidden)[(size_t)n * 4 + c];
        fma4_64(h1, xc, W1 + (4 + 4 * c) * 64);
    }
    #pragma unroll
    for (int j = 0; j < 64; j++) h1[j] = fmaxf(h1[j], 0.f);

    float o[ND];
    mlp_tail(h1, o, W2, b2, W3, b3);

    #pragma unroll
    for (int k = 0; k < ND; k++) Ol[tid * ND + k] = o[k];
    __syncthreads();

    // coalesced fp16 pack: 256 nodes x 16 u32
    unsigned int* mo = msgh + (size_t)blockIdx.x * 256 * MROW;
    #pragma unroll
    for (int u = 0; u < MROW; u++) {
        const int idx = u * 256 + tid;
        const int nn = idx >> 4, slot = idx & 15;
        const int c2 = slot * 2;
        float v0 = 0.f, v1 = 0.f;
        if (c2 < ND) { v0 = Ol[nn * ND + c2]; v1 = Ol[nn * ND + c2 + 1]; }
        __half2 h = __floats2half2_rn(v0, v1);
        mo[idx] = *reinterpret_cast<unsigned int*>(&h);
    }
}

// ---------------------------------------------------------------------------
// Kernel 2: bucket fill (block-major). Each block counting-sorts its 4096
// edges by bucket in LDS and writes ONE contiguous coalesced 16 KB run.
// ---------------------------------------------------------------------------
__global__ __launch_bounds__(256) void bucket_fill_kernel(
    const int* __restrict__ senders, const int* __restrict__ receivers,
    unsigned int* __restrict__ bucketed, unsigned int* __restrict__ tab)
{
    __shared__ int cnt[NBUCK];
    __shared__ int boff[NBUCK];
    __shared__ int lcur[NBUCK];
    __shared__ int psum[256];
    __shared__ unsigned int sorted[EPB];   // 16 KB
    const int tid = threadIdx.x;
    const int blk = blockIdx.x;

    cnt[tid] = 0; cnt[256 + tid] = 0;
    __syncthreads();

    int rr[EPT], ss[EPT];
    const int base = blk * EPB;
    #pragma unroll
    for (int k = 0; k < EPT; k++) {
        rr[k] = receivers[base + k * 256 + tid];
        ss[k] = senders[base + k * 256 + tid];
        atomicAdd(&cnt[rr[k] >> BSHIFT], 1);
    }
    __syncthreads();

    const int c0 = cnt[2 * tid], c1 = cnt[2 * tid + 1];
    psum[tid] = c0 + c1;
    __syncthreads();
    #pragma unroll
    for (int off = 1; off < 256; off <<= 1) {
        int t = (tid >= off) ? psum[tid - off] : 0;
        __syncthreads();
        psum[tid] += t;
        __syncthreads();
    }
    const int ex = psum[tid] - (c0 + c1);
    boff[2 * tid] = ex;       boff[2 * tid + 1] = ex + c0;
    lcur[2 * tid] = ex;       lcur[2 * tid + 1] = ex + c0;
    __syncthreads();

    tab[(size_t)blk * NBUCK + tid] =
        ((unsigned int)boff[tid] << 16) | (unsigned int)cnt[tid];
    tab[(size_t)blk * NBUCK + 256 + tid] =
        ((unsigned int)boff[256 + tid] << 16) | (unsigned int)cnt[256 + tid];

    #pragma unroll
    for (int k = 0; k < EPT; k++) {
        const int b = rr[k] >> BSHIFT;
        const int slot = atomicAdd(&lcur[b], 1);
        sorted[slot] = (((unsigned int)(rr[k] & (RPB - 1))) << SBITS) | (unsigned int)ss[k];
    }
    __syncthreads();

    const uint4* s4 = reinterpret_cast<const uint4*>(sorted);
    uint4* o4 = reinterpret_cast<uint4*>(bucketed + (size_t)blk * EPB);
    #pragma unroll
    for (int k = 0; k < EPB / 4 / 256; k++)
        o4[k * 256 + tid] = s4[k * 256 + tid];
}

// ---------------------------------------------------------------------------
// Kernel 3: transpose tab [FBLK][NBUCK] -> tabT [NBUCK][FBLK] (LDS-tiled).
// ---------------------------------------------------------------------------
__global__ __launch_bounds__(256) void transpose_tab_kernel(
    const unsigned int* __restrict__ in, unsigned int* __restrict__ out)
{
    __shared__ unsigned int t[32][33];
    const int tx = threadIdx.x & 31;
    const int ty0 = (threadIdx.x >> 5) * 4;
    const int bb = blockIdx.x * 32;   // bucket base
    const int kb = blockIdx.y * 32;   // blk base
    #pragma unroll
    for (int k = 0; k < 4; k++)
        t[ty0 + k][tx] = in[(size_t)(kb + ty0 + k) * NBUCK + bb + tx];
    __syncthreads();
    #pragma unroll
    for (int k = 0; k < 4; k++)
        out[(size_t)(bb + ty0 + k) * FBLK + kb + tx] = t[tx][ty0 + k];
}

// ---------------------------------------------------------------------------
// Kernel 4: fused per-bucket group + gather (round-6 form). One block
// (1024 thr) per bucket; group by receiver in LDS; fp16 line gather.
// ---------------------------------------------------------------------------
__global__ __launch_bounds__(1024) void bucket_gather_kernel(
    const unsigned int* __restrict__ bucketed,
    const unsigned int* __restrict__ tabT,
    const unsigned int* __restrict__ msgh, float* __restrict__ agg)
{
    __shared__ unsigned int elds[CAP];
    __shared__ int dcnt[RPB];
    __shared__ int dcur[RPB];
    const int tid = threadIdx.x;
    const int b = blockIdx.x;

    const unsigned int tv = tabT[(size_t)b * FBLK + tid];
    const int segc = tv & 0xFFFF;
    const unsigned int* seg = bucketed + (size_t)tid * EPB + (tv >> 16);

    if (tid < RPB) dcnt[tid] = 0;
    __syncthreads();
    for (int i = 0; i < segc; i++)
        atomicAdd(&dcnt[seg[i] >> SBITS], 1);
    __syncthreads();
    if (tid < RPB) dcur[tid] = dcnt[tid];
    __syncthreads();
    #pragma unroll
    for (int off = 1; off < RPB; off <<= 1) {
        int t = 0;
        if (tid < RPB && tid >= off) t = dcur[tid - off];
        __syncthreads();
        if (tid < RPB) dcur[tid] += t;
        __syncthreads();
    }
    if (tid < RPB) dcur[tid] -= dcnt[tid];   // exclusive
    __syncthreads();
    for (int i = 0; i < segc; i++) {
        const unsigned int v = seg[i];
        const int slot = atomicAdd(&dcur[v >> SBITS], 1);
        if (slot < CAP) elds[slot] = v & SMASK;
    }
    __syncthreads();

    // per-receiver gather: half-wave groups; lanes 0..9 handle comps 2c,2c+1
    const int hw = tid >> 5;          // 0..31
    const int c = tid & 31;
    const bool act = c < ND / 2;
    for (int rl = hw; rl < RPB; rl += 32) {
        int end = dcur[rl];
        const int cv = dcnt[rl];
        int st = end - cv;
        if (st < 0) st = 0;
        if (end > CAP) end = CAP;
        float a00 = 0.f, a01 = 0.f, a10 = 0.f, a11 = 0.f;
        float a20 = 0.f, a21 = 0.f, a30 = 0.f, a31 = 0.f;
        int i = st;
        for (; i + 3 < end; i += 4) {
            const int s0 = elds[i + 0];
            const int s1 = elds[i + 1];
            const int s2 = elds[i + 2];
            const int s3 = elds[i + 3];
            if (act) {
                const unsigned int w0 = msgh[s0 * MROW + c];
                const unsigned int w1 = msgh[s1 * MROW + c];
                const unsigned int w2 = msgh[s2 * MROW + c];
                const unsigned int w3 = msgh[s3 * MROW + c];
                const float2 f0 = __half22float2(*reinterpret_cast<const __half2*>(&w0));
                const float2 f1 = __half22float2(*reinterpret_cast<const __half2*>(&w1));
                const float2 f2 = __half22float2(*reinterpret_cast<const __half2*>(&w2));
                const float2 f3 = __half22float2(*reinterpret_cast<const __half2*>(&w3));
                a00 += f0.x; a01 += f0.y;
                a10 += f1.x; a11 += f1.y;
                a20 += f2.x; a21 += f2.y;
                a30 += f3.x; a31 += f3.y;
            }
        }
        for (; i < end; i++) {
            const int s = elds[i];
            if (act) {
                const unsigned int w = msgh[s * MROW + c];
                const float2 f = __half22float2(*reinterpret_cast<const __half2*>(&w));
                a00 += f.x; a01 += f.y;
            }
        }
        if (act) {
            float2 r = make_float2((a00 + a10) + (a20 + a30),
                                   (a01 + a11) + (a21 + a31));
            *reinterpret_cast<float2*>(&agg[((size_t)b * RPB + rl) * ND + 2 * c]) = r;
        }
    }
}

// ---------------------------------------------------------------------------
// Kernel 5: node output MLP (40 -> 64 -> 32 -> 20), 1 thread = 1 node.
// Weights via uniform (scalar-pipe) loads; zero LDS.
// ---------------------------------------------------------------------------
__global__ __launch_bounds__(256) void node_mlp_kernel(
    const float* __restrict__ logits, const float* __restrict__ hidden,
    const float* __restrict__ agg,
    const float* __restrict__ W1, const float* __restrict__ b1,
    const float* __restrict__ W2, const float* __restrict__ b2,
    const float* __restrict__ W3, const float* __restrict__ b3,
    float* __restrict__ out)
{
    const int tid = threadIdx.x;
    const int n = blockIdx.x * 256 + tid;

    float h1[64];
    #pragma unroll
    for (int j = 0; j < 64; j++) h1[j] = b1[j];

    {   // logits rows 0..3
        const float4 xc = reinterpret_cast<const float4*>(logits)[n];
        fma4_64(h1, xc, W1);
    }
    #pragma unroll 1
    for (int c = 0; c < 4; c++) {   // hidden rows 4..19
        const float4 xc = reinterpret_cast<const float4*>(hidden)[(size_t)n * 4 + c];
        fma4_64(h1, xc, W1 + (4 + 4 * c) * 64);
    }
    #pragma unroll 1
    for (int c = 0; c < 5; c++) {   // agg rows 20..39
        const float4 xc = reinterpret_cast<const float4*>(agg)[(size_t)n * 5 + c];
        fma4_64(h1, xc, W1 + (ND + 4 * c) * 64);
    }
    #pragma unroll
    for (int j = 0; j < 64; j++) h1[j] = fmaxf(h1[j], 0.f);

    float o[ND];
    mlp_tail(h1, o, W2, b2, W3, b3);

    // updated_logits: coalesced float4 per node
    reinterpret_cast<float4*>(out)[n] = make_float4(o[0], o[1], o[2], o[3]);
    // updated_hidden
    float4* ho = reinterpret_cast<float4*>(out + (size_t)NN * NLOGIT + (size_t)n * NHID);
    #pragma unroll
    for (int k = 0; k < 4; k++)
        ho[k] = make_float4(o[4 + k * 4 + 0], o[4 + k * 4 + 1],
                            o[4 + k * 4 + 2], o[4 + k * 4 + 3]);
}

extern "C" void kernel_launch(void* const* d_in, const int* in_sizes, int n_in,
                              void* d_out, int out_size, void* d_ws, size_t ws_size,
                              hipStream_t stream) {
    const float* logits   = (const float*)d_in[0];
    const float* hidden   = (const float*)d_in[1];
    const int*   senders  = (const int*)d_in[2];
    const int*   receivers= (const int*)d_in[3];
    const float* We1 = (const float*)d_in[4];
    const float* be1 = (const float*)d_in[5];
    const float* We2 = (const float*)d_in[6];
    const float* be2 = (const float*)d_in[7];
    const float* We3 = (const float*)d_in[8];
    const float* be3 = (const float*)d_in[9];
    const float* Wn1 = (const float*)d_in[10];
    const float* bn1 = (const float*)d_in[11];
    const float* Wn2 = (const float*)d_in[12];
    const float* bn2 = (const float*)d_in[13];
    const float* Wn3 = (const float*)d_in[14];
    const float* bn3 = (const float*)d_in[15];
    float* out = (float*)d_out;

    // Workspace layout (~58.6 MB)
    unsigned int* msgh = (unsigned int*)d_ws;          // NN*MROW u32 (16.8 MB, 64B rows)
    float* agg = (float*)(msgh + (size_t)NN * MROW);   // NN*ND floats (21 MB)
    unsigned int* bucketed = (unsigned int*)(agg + (size_t)NN * ND);  // NE u32 (16.8 MB)
    unsigned int* tab  = bucketed + NE;                // FBLK*NBUCK u32 (2 MB)
    unsigned int* tabT = tab + (size_t)FBLK * NBUCK;   // NBUCK*FBLK u32 (2 MB)

    msg_mlp_kernel<<<NN / 256, 256, 0, stream>>>(
        logits, hidden, We1, be1, We2, be2, We3, be3, msgh);
    bucket_fill_kernel<<<FBLK, 256, 0, stream>>>(senders, receivers, bucketed, tab);
    transpose_tab_kernel<<<dim3(NBUCK / 32, FBLK / 32), 256, 0, stream>>>(tab, tabT);
    bucket_gather_kernel<<<NBUCK, 1024, 0, stream>>>(bucketed, tabT, msgh, agg);
    node_mlp_kernel<<<NN / 256, 256, 0, stream>>>(
        logits, hidden, agg, Wn1, bn1, Wn2, bn2, Wn3, bn3, out);
}